// Round 1
// baseline (1138.836 us; speedup 1.0000x reference)
//
#include <hip/hip_runtime.h>
#include <hip/hip_bf16.h>

// GCN: 4 layers. Per layer: t = h @ W ; out[i] = dinv[i]*(sum_{src->i} dinv[src]*t[src])
//                                               + dinv[i]^2*t[i] + b ; relu (not last)
// CSR built per call (workspace is poisoned every call).

#define NNODES 100000
#define NEDGES 1600000

// ---------------- CSR build ----------------

__global__ void zero_ints(int* p, int n) {
    int i = blockIdx.x * blockDim.x + threadIdx.x;
    if (i < n) p[i] = 0;
}

__global__ void count_deg(const int* __restrict__ dst, int* __restrict__ deg, int e) {
    int i = blockIdx.x * blockDim.x + threadIdx.x;
    if (i < e) atomicAdd(&deg[dst[i]], 1);
}

__global__ void compute_dinv(const int* __restrict__ deg, float* __restrict__ dinv, int n) {
    int i = blockIdx.x * blockDim.x + threadIdx.x;
    if (i < n) dinv[i] = rsqrtf((float)(deg[i] + 1));   // +1 self loop
}

// exclusive scan of deg -> row_ptr, in 3 kernels. chunk = 1024 elems/block.
__global__ void scan_block_sums(const int* __restrict__ deg, int* __restrict__ bsum, int n) {
    __shared__ int sd[256];
    int t = threadIdx.x;
    int base = blockIdx.x * 1024 + t * 4;
    int s = 0;
#pragma unroll
    for (int j = 0; j < 4; j++) { int i = base + j; if (i < n) s += deg[i]; }
    sd[t] = s; __syncthreads();
    for (int off = 128; off > 0; off >>= 1) {
        if (t < off) sd[t] += sd[t + off];
        __syncthreads();
    }
    if (t == 0) bsum[blockIdx.x] = sd[0];
}

__global__ void scan_small_exclusive(int* __restrict__ bsum, int nb,
                                     int* __restrict__ row_ptr, int n, int e) {
    __shared__ int sd[256];
    int t = threadIdx.x;
    int v = (t < nb) ? bsum[t] : 0;
    sd[t] = v; __syncthreads();
    for (int off = 1; off < 256; off <<= 1) {
        int x = (t >= off) ? sd[t - off] : 0;
        __syncthreads();
        sd[t] += x;
        __syncthreads();
    }
    if (t < nb) bsum[t] = sd[t] - v;   // exclusive
    if (t == 0) row_ptr[n] = e;
}

__global__ void scan_write(const int* __restrict__ deg, const int* __restrict__ bsum,
                           int* __restrict__ row_ptr, int n) {
    __shared__ int sd[256];
    int t = threadIdx.x;
    int base = blockIdx.x * 1024 + t * 4;
    int v[4]; int s = 0;
#pragma unroll
    for (int j = 0; j < 4; j++) { int i = base + j; v[j] = (i < n) ? deg[i] : 0; s += v[j]; }
    sd[t] = s; __syncthreads();
    for (int off = 1; off < 256; off <<= 1) {
        int x = (t >= off) ? sd[t - off] : 0;
        __syncthreads();
        sd[t] += x;
        __syncthreads();
    }
    int run = bsum[blockIdx.x] + (sd[t] - s);
#pragma unroll
    for (int j = 0; j < 4; j++) {
        int i = base + j;
        if (i < n) row_ptr[i] = run;
        run += v[j];
    }
}

__global__ void fill_csr(const int* __restrict__ src, const int* __restrict__ dst,
                         const int* __restrict__ row_ptr, int* __restrict__ fill,
                         int* __restrict__ col, int e) {
    int i = blockIdx.x * blockDim.x + threadIdx.x;
    if (i < e) {
        int d = dst[i];
        int o = atomicAdd(&fill[d], 1);
        col[row_ptr[d] + o] = src[i];
    }
}

// ---------------- dense GEMM: T = A @ W, A [nrows x 128], W [128 x BN] ----------------
// BM=64, BK=32, 256 threads, per-thread 4x(BN/16) register tile.

template <int BN>
__global__ __launch_bounds__(256) void gemm_k128(const float* __restrict__ A,
                                                 const float* __restrict__ W,
                                                 float* __restrict__ T, int nrows) {
    constexpr int BM = 64, BK = 32, K = 128;
    constexpr int TM = 4, TN = BN / 16;
    __shared__ float As[BK][BM + 4];   // transposed A tile; stride 68 floats (16B-mult)
    __shared__ float Bs[BK][BN];

    int tid = threadIdx.x;
    int block_row = blockIdx.x * BM;
    int tx = tid % 16, ty = tid / 16;

    float acc[TM][TN];
#pragma unroll
    for (int m = 0; m < TM; m++)
#pragma unroll
        for (int n = 0; n < TN; n++) acc[m][n] = 0.f;

    for (int k0 = 0; k0 < K; k0 += BK) {
        // A tile: 64 rows x 32 cols = 512 float4, 2 per thread
#pragma unroll
        for (int i = 0; i < 2; i++) {
            int idx = tid + i * 256;
            int r = idx / 8, c4 = idx % 8;
            int grow = block_row + r;
            float4 v;
            if (grow < nrows) v = *(const float4*)(A + (size_t)grow * K + k0 + c4 * 4);
            else              v = make_float4(0.f, 0.f, 0.f, 0.f);
            As[c4 * 4 + 0][r] = v.x; As[c4 * 4 + 1][r] = v.y;
            As[c4 * 4 + 2][r] = v.z; As[c4 * 4 + 3][r] = v.w;
        }
        // W tile: 32 x BN
#pragma unroll
        for (int i = 0; i < BK * BN / 4 / 256; i++) {
            int idx = tid + i * 256;
            int r = idx / (BN / 4), c4 = idx % (BN / 4);
            *(float4*)&Bs[r][c4 * 4] = *(const float4*)(W + (size_t)(k0 + r) * BN + c4 * 4);
        }
        __syncthreads();

#pragma unroll
        for (int k = 0; k < BK; k++) {
            float a[TM], b[TN];
            *(float4*)a = *(const float4*)&As[k][ty * TM];
#pragma unroll
            for (int n = 0; n < TN; n += 4)
                *(float4*)&b[n] = *(const float4*)&Bs[k][tx * TN + n];
#pragma unroll
            for (int m = 0; m < TM; m++)
#pragma unroll
                for (int n = 0; n < TN; n++) acc[m][n] += a[m] * b[n];
        }
        __syncthreads();
    }

#pragma unroll
    for (int m = 0; m < TM; m++) {
        int grow = block_row + ty * TM + m;
        if (grow < nrows) {
#pragma unroll
            for (int n = 0; n < TN; n += 4)
                *(float4*)(T + (size_t)grow * BN + tx * TN + n) = *(const float4*)&acc[m][n];
        }
    }
}

// ---------------- aggregation: wave per node ----------------

template <int F, bool RELU>
__global__ __launch_bounds__(256) void agg_kernel(const float* __restrict__ t,
                                                  const int* __restrict__ row_ptr,
                                                  const int* __restrict__ col,
                                                  const float* __restrict__ dinv,
                                                  const float* __restrict__ bias,
                                                  float* __restrict__ out, int n) {
    int wave = threadIdx.x >> 6;
    int lane = threadIdx.x & 63;
    int node = blockIdx.x * 4 + wave;
    if (node >= n) return;
    int r0 = row_ptr[node], r1 = row_ptr[node + 1];

    if constexpr (F == 128) {
        const float2* tp = (const float2*)t;
        float acc0 = 0.f, acc1 = 0.f;
        for (int p = r0; p < r1; p++) {
            int c = col[p];
            float w = dinv[c];
            float2 v = tp[(size_t)c * 64 + lane];
            acc0 += w * v.x;
            acc1 += w * v.y;
        }
        float di = dinv[node];
        float2 sv = tp[(size_t)node * 64 + lane];
        float o0 = di * acc0 + di * di * sv.x + bias[lane * 2];
        float o1 = di * acc1 + di * di * sv.y + bias[lane * 2 + 1];
        if (RELU) { o0 = fmaxf(o0, 0.f); o1 = fmaxf(o1, 0.f); }
        float2 r; r.x = o0; r.y = o1;
        ((float2*)out)[(size_t)node * 64 + lane] = r;
    } else {  // F == 64
        float acc = 0.f;
        for (int p = r0; p < r1; p++) {
            int c = col[p];
            acc += dinv[c] * t[(size_t)c * 64 + lane];
        }
        float di = dinv[node];
        float o = di * acc + di * di * t[(size_t)node * 64 + lane] + bias[lane];
        if (RELU) o = fmaxf(o, 0.f);
        out[(size_t)node * 64 + lane] = o;
    }
}

// ---------------- launch ----------------

extern "C" void kernel_launch(void* const* d_in, const int* in_sizes, int n_in,
                              void* d_out, int out_size, void* d_ws, size_t ws_size,
                              hipStream_t stream) {
    const int N = NNODES, E = NEDGES;
    const float* x   = (const float*)d_in[0];
    const int*   ei  = (const int*)d_in[1];
    const int*   src = ei;
    const int*   dst = ei + E;
    const float* W1  = (const float*)d_in[2];
    const float* b1  = (const float*)d_in[3];
    const float* Wm1 = (const float*)d_in[4];
    const float* bm1 = (const float*)d_in[5];
    const float* Wm2 = (const float*)d_in[6];
    const float* bm2 = (const float*)d_in[7];
    const float* W2  = (const float*)d_in[8];
    const float* b2  = (const float*)d_in[9];
    float* out = (float*)d_out;

    // workspace layout (all offsets multiples of 4 elems -> 16B aligned)
    int* deg     = (int*)d_ws;               // N
    int* fill    = deg + N;                  // N
    int* row_ptr = fill + N;                 // N+4 (slot)
    int* bsum    = row_ptr + (N + 4);        // 256
    int* col     = bsum + 256;               // E
    float* dinv  = (float*)(col + E);        // N
    float* t     = dinv + N;                 // N*128
    float* bufA  = t + (size_t)N * 128;      // N*128

    const int NBLK = (N + 1023) / 1024;      // 98
    const int EB   = (E + 255) / 256;

    zero_ints<<<(2 * N + 255) / 256, 256, 0, stream>>>(deg, 2 * N);
    count_deg<<<EB, 256, 0, stream>>>(dst, deg, E);
    compute_dinv<<<(N + 255) / 256, 256, 0, stream>>>(deg, dinv, N);
    scan_block_sums<<<NBLK, 256, 0, stream>>>(deg, bsum, N);
    scan_small_exclusive<<<1, 256, 0, stream>>>(bsum, NBLK, row_ptr, N, E);
    scan_write<<<NBLK, 256, 0, stream>>>(deg, bsum, row_ptr, N);
    fill_csr<<<EB, 256, 0, stream>>>(src, dst, row_ptr, fill, col, E);

    const int GB = (N + 63) / 64;            // gemm blocks
    const int AB = (N + 3) / 4;              // agg blocks (4 waves/block)

    // layer 1: x -> bufA
    gemm_k128<128><<<GB, 256, 0, stream>>>(x, W1, t, N);
    agg_kernel<128, true><<<AB, 256, 0, stream>>>(t, row_ptr, col, dinv, b1, bufA, N);
    // layer 2: bufA -> bufA
    gemm_k128<128><<<GB, 256, 0, stream>>>(bufA, Wm1, t, N);
    agg_kernel<128, true><<<AB, 256, 0, stream>>>(t, row_ptr, col, dinv, bm1, bufA, N);
    // layer 3: bufA -> bufA
    gemm_k128<128><<<GB, 256, 0, stream>>>(bufA, Wm2, t, N);
    agg_kernel<128, true><<<AB, 256, 0, stream>>>(t, row_ptr, col, dinv, bm2, bufA, N);
    // layer 4: bufA -> out (no relu)
    gemm_k128<64><<<GB, 256, 0, stream>>>(bufA, W2, t, N);
    agg_kernel<64, false><<<AB, 256, 0, stream>>>(t, row_ptr, col, dinv, b2, out, N);
}

// Round 2
// 967.556 us; speedup vs baseline: 1.1770x; 1.1770x over previous
//
#include <hip/hip_runtime.h>
#include <hip/hip_bf16.h>

// GCN 4 layers. Per layer: t_pre = dinv[row] * (H @ W)  (fused in GEMM epilogue)
//              out[i] = dinv[i] * ( sum_{src->i} t_pre[src] + t_pre[i] ) + b ; relu (not last)
// CSR built per call (workspace is poisoned every call).

#define NNODES 100000
#define NEDGES 1600000

// ---------------- CSR build ----------------

__global__ void zero_ints(int* p, int n) {
    int i = blockIdx.x * blockDim.x + threadIdx.x;
    if (i < n) p[i] = 0;
}

__global__ void count_deg(const int* __restrict__ dst, int* __restrict__ deg, int e) {
    int i = blockIdx.x * blockDim.x + threadIdx.x;
    if (i < e) atomicAdd(&deg[dst[i]], 1);
}

__global__ void compute_dinv(const int* __restrict__ deg, float* __restrict__ dinv, int n) {
    int i = blockIdx.x * blockDim.x + threadIdx.x;
    if (i < n) dinv[i] = rsqrtf((float)(deg[i] + 1));   // +1 self loop
}

// exclusive scan of deg -> row_ptr, in 3 kernels. chunk = 1024 elems/block.
__global__ void scan_block_sums(const int* __restrict__ deg, int* __restrict__ bsum, int n) {
    __shared__ int sd[256];
    int t = threadIdx.x;
    int base = blockIdx.x * 1024 + t * 4;
    int s = 0;
#pragma unroll
    for (int j = 0; j < 4; j++) { int i = base + j; if (i < n) s += deg[i]; }
    sd[t] = s; __syncthreads();
    for (int off = 128; off > 0; off >>= 1) {
        if (t < off) sd[t] += sd[t + off];
        __syncthreads();
    }
    if (t == 0) bsum[blockIdx.x] = sd[0];
}

__global__ void scan_small_exclusive(int* __restrict__ bsum, int nb,
                                     int* __restrict__ row_ptr, int n, int e) {
    __shared__ int sd[256];
    int t = threadIdx.x;
    int v = (t < nb) ? bsum[t] : 0;
    sd[t] = v; __syncthreads();
    for (int off = 1; off < 256; off <<= 1) {
        int x = (t >= off) ? sd[t - off] : 0;
        __syncthreads();
        sd[t] += x;
        __syncthreads();
    }
    if (t < nb) bsum[t] = sd[t] - v;   // exclusive
    if (t == 0) row_ptr[n] = e;
}

__global__ void scan_write(const int* __restrict__ deg, const int* __restrict__ bsum,
                           int* __restrict__ row_ptr, int n) {
    __shared__ int sd[256];
    int t = threadIdx.x;
    int base = blockIdx.x * 1024 + t * 4;
    int v[4]; int s = 0;
#pragma unroll
    for (int j = 0; j < 4; j++) { int i = base + j; v[j] = (i < n) ? deg[i] : 0; s += v[j]; }
    sd[t] = s; __syncthreads();
    for (int off = 1; off < 256; off <<= 1) {
        int x = (t >= off) ? sd[t - off] : 0;
        __syncthreads();
        sd[t] += x;
        __syncthreads();
    }
    int run = bsum[blockIdx.x] + (sd[t] - s);
#pragma unroll
    for (int j = 0; j < 4; j++) {
        int i = base + j;
        if (i < n) row_ptr[i] = run;
        run += v[j];
    }
}

__global__ void fill_csr(const int* __restrict__ src, const int* __restrict__ dst,
                         const int* __restrict__ row_ptr, int* __restrict__ fill,
                         int* __restrict__ col, int e) {
    int i = blockIdx.x * blockDim.x + threadIdx.x;
    if (i < e) {
        int d = dst[i];
        int o = atomicAdd(&fill[d], 1);
        col[row_ptr[d] + o] = src[i];
    }
}

// ---------------- dense GEMM: T = dinv[row] * (A @ W) ----------------
// BM=128, BK=16, 256 threads (16x16), per-thread 8 x TN register tile.

template <int BN>
__global__ __launch_bounds__(256) void gemm_k128_ps(const float* __restrict__ A,
                                                    const float* __restrict__ W,
                                                    const float* __restrict__ dinv,
                                                    float* __restrict__ T, int nrows) {
    constexpr int BM = 128, BK = 16, K = 128;
    constexpr int TM = 8, TN = BN / 16;
    __shared__ float As[BK][BM + 4];   // transposed A tile
    __shared__ float Bs[BK][BN];

    int tid = threadIdx.x;
    int block_row = blockIdx.x * BM;
    int tx = tid % 16, ty = tid / 16;

    float acc[TM][TN];
#pragma unroll
    for (int m = 0; m < TM; m++)
#pragma unroll
        for (int n = 0; n < TN; n++) acc[m][n] = 0.f;

    for (int k0 = 0; k0 < K; k0 += BK) {
        // A tile: 128 rows x 16 cols = 512 float4, 2 per thread (transpose on store)
#pragma unroll
        for (int i = 0; i < 2; i++) {
            int idx = tid + i * 256;
            int r = idx / 4, c4 = idx % 4;
            int grow = block_row + r;
            float4 v;
            if (grow < nrows) v = *(const float4*)(A + (size_t)grow * K + k0 + c4 * 4);
            else              v = make_float4(0.f, 0.f, 0.f, 0.f);
            As[c4 * 4 + 0][r] = v.x; As[c4 * 4 + 1][r] = v.y;
            As[c4 * 4 + 2][r] = v.z; As[c4 * 4 + 3][r] = v.w;
        }
        // W tile: BK x BN
#pragma unroll
        for (int i = 0; i < BK * BN / 4 / 256; i++) {
            int idx = tid + i * 256;
            int r = idx / (BN / 4), c4 = idx % (BN / 4);
            *(float4*)&Bs[r][c4 * 4] = *(const float4*)(W + (size_t)(k0 + r) * BN + c4 * 4);
        }
        __syncthreads();

#pragma unroll
        for (int k = 0; k < BK; k++) {
            float a[TM], b[TN];
            *(float4*)&a[0] = *(const float4*)&As[k][ty * TM];
            *(float4*)&a[4] = *(const float4*)&As[k][ty * TM + 4];
#pragma unroll
            for (int n = 0; n < TN; n += 4)
                *(float4*)&b[n] = *(const float4*)&Bs[k][tx * TN + n];
#pragma unroll
            for (int m = 0; m < TM; m++)
#pragma unroll
                for (int n = 0; n < TN; n++) acc[m][n] += a[m] * b[n];
        }
        __syncthreads();
    }

#pragma unroll
    for (int m = 0; m < TM; m++) {
        int grow = block_row + ty * TM + m;
        if (grow < nrows) {
            float s = dinv[grow];
#pragma unroll
            for (int n = 0; n < TN; n += 4) {
                float4 v;
                v.x = acc[m][n] * s; v.y = acc[m][n + 1] * s;
                v.z = acc[m][n + 2] * s; v.w = acc[m][n + 3] * s;
                *(float4*)(T + (size_t)grow * BN + tx * TN + n) = v;
            }
        }
    }
}

// ---------------- aggregation: wave per node, half-wave per neighbor row ----------------
// F=128: lane = (half, q); row fetched as float4 per lane (32 lanes x 16B = full row).
// Main loop: 8 edges/iter = 4 independent gathers in flight.

template <bool RELU>
__global__ __launch_bounds__(256) void agg128(const float* __restrict__ tpre,
                                              const int* __restrict__ row_ptr,
                                              const int* __restrict__ col,
                                              const float* __restrict__ dinv,
                                              const float* __restrict__ bias,
                                              float* __restrict__ out, int n) {
    int wave = threadIdx.x >> 6;
    int lane = threadIdx.x & 63;
    int node = blockIdx.x * 4 + wave;
    if (node >= n) return;
    int half = lane >> 5, q = lane & 31;
    int r0 = row_ptr[node], r1 = row_ptr[node + 1];
    const float4* t4 = (const float4*)tpre;

    float4 a0 = make_float4(0.f, 0.f, 0.f, 0.f);
    float4 a1 = make_float4(0.f, 0.f, 0.f, 0.f);
    float4 a2 = make_float4(0.f, 0.f, 0.f, 0.f);
    float4 a3 = make_float4(0.f, 0.f, 0.f, 0.f);

    int p = r0;
    for (; p + 8 <= r1; p += 8) {
        int c0 = col[p + half];
        int c1 = col[p + 2 + half];
        int c2 = col[p + 4 + half];
        int c3 = col[p + 6 + half];
        float4 v0 = t4[(size_t)c0 * 32 + q];
        float4 v1 = t4[(size_t)c1 * 32 + q];
        float4 v2 = t4[(size_t)c2 * 32 + q];
        float4 v3 = t4[(size_t)c3 * 32 + q];
        a0.x += v0.x; a0.y += v0.y; a0.z += v0.z; a0.w += v0.w;
        a1.x += v1.x; a1.y += v1.y; a1.z += v1.z; a1.w += v1.w;
        a2.x += v2.x; a2.y += v2.y; a2.z += v2.z; a2.w += v2.w;
        a3.x += v3.x; a3.y += v3.y; a3.z += v3.z; a3.w += v3.w;
    }
    for (; p < r1; p += 4) {          // masked tail, 4 edges/iter
        int i0 = p + half, i1 = p + 2 + half;
        float m0 = (i0 < r1) ? 1.f : 0.f;
        float m1 = (i1 < r1) ? 1.f : 0.f;
        int c0 = col[i0 < r1 ? i0 : r1 - 1];
        int c1 = col[i1 < r1 ? i1 : r1 - 1];
        float4 v0 = t4[(size_t)c0 * 32 + q];
        float4 v1 = t4[(size_t)c1 * 32 + q];
        a0.x += m0 * v0.x; a0.y += m0 * v0.y; a0.z += m0 * v0.z; a0.w += m0 * v0.w;
        a1.x += m1 * v1.x; a1.y += m1 * v1.y; a1.z += m1 * v1.z; a1.w += m1 * v1.w;
    }

    float4 s;
    s.x = (a0.x + a1.x) + (a2.x + a3.x);
    s.y = (a0.y + a1.y) + (a2.y + a3.y);
    s.z = (a0.z + a1.z) + (a2.z + a3.z);
    s.w = (a0.w + a1.w) + (a2.w + a3.w);
    s.x += __shfl_xor(s.x, 32);
    s.y += __shfl_xor(s.y, 32);
    s.z += __shfl_xor(s.z, 32);
    s.w += __shfl_xor(s.w, 32);

    if (half == 0) {
        float4 own = t4[(size_t)node * 32 + q];
        float di = dinv[node];
        float4 b4 = ((const float4*)bias)[q];
        float4 o;
        o.x = di * (s.x + own.x) + b4.x;
        o.y = di * (s.y + own.y) + b4.y;
        o.z = di * (s.z + own.z) + b4.z;
        o.w = di * (s.w + own.w) + b4.w;
        if (RELU) {
            o.x = fmaxf(o.x, 0.f); o.y = fmaxf(o.y, 0.f);
            o.z = fmaxf(o.z, 0.f); o.w = fmaxf(o.w, 0.f);
        }
        ((float4*)out)[(size_t)node * 32 + q] = o;
    }
}

// F=64 variant: float2 per lane.
template <bool RELU>
__global__ __launch_bounds__(256) void agg64(const float* __restrict__ tpre,
                                             const int* __restrict__ row_ptr,
                                             const int* __restrict__ col,
                                             const float* __restrict__ dinv,
                                             const float* __restrict__ bias,
                                             float* __restrict__ out, int n) {
    int wave = threadIdx.x >> 6;
    int lane = threadIdx.x & 63;
    int node = blockIdx.x * 4 + wave;
    if (node >= n) return;
    int half = lane >> 5, q = lane & 31;
    int r0 = row_ptr[node], r1 = row_ptr[node + 1];
    const float2* t2 = (const float2*)tpre;

    float2 a0 = make_float2(0.f, 0.f), a1 = make_float2(0.f, 0.f);
    float2 a2 = make_float2(0.f, 0.f), a3 = make_float2(0.f, 0.f);

    int p = r0;
    for (; p + 8 <= r1; p += 8) {
        int c0 = col[p + half];
        int c1 = col[p + 2 + half];
        int c2 = col[p + 4 + half];
        int c3 = col[p + 6 + half];
        float2 v0 = t2[(size_t)c0 * 32 + q];
        float2 v1 = t2[(size_t)c1 * 32 + q];
        float2 v2 = t2[(size_t)c2 * 32 + q];
        float2 v3 = t2[(size_t)c3 * 32 + q];
        a0.x += v0.x; a0.y += v0.y;
        a1.x += v1.x; a1.y += v1.y;
        a2.x += v2.x; a2.y += v2.y;
        a3.x += v3.x; a3.y += v3.y;
    }
    for (; p < r1; p += 4) {
        int i0 = p + half, i1 = p + 2 + half;
        float m0 = (i0 < r1) ? 1.f : 0.f;
        float m1 = (i1 < r1) ? 1.f : 0.f;
        int c0 = col[i0 < r1 ? i0 : r1 - 1];
        int c1 = col[i1 < r1 ? i1 : r1 - 1];
        float2 v0 = t2[(size_t)c0 * 32 + q];
        float2 v1 = t2[(size_t)c1 * 32 + q];
        a0.x += m0 * v0.x; a0.y += m0 * v0.y;
        a1.x += m1 * v1.x; a1.y += m1 * v1.y;
    }

    float2 s;
    s.x = (a0.x + a1.x) + (a2.x + a3.x);
    s.y = (a0.y + a1.y) + (a2.y + a3.y);
    s.x += __shfl_xor(s.x, 32);
    s.y += __shfl_xor(s.y, 32);

    if (half == 0) {
        float2 own = t2[(size_t)node * 32 + q];
        float di = dinv[node];
        float2 b2 = ((const float2*)bias)[q];
        float2 o;
        o.x = di * (s.x + own.x) + b2.x;
        o.y = di * (s.y + own.y) + b2.y;
        if (RELU) { o.x = fmaxf(o.x, 0.f); o.y = fmaxf(o.y, 0.f); }
        ((float2*)out)[(size_t)node * 32 + q] = o;
    }
}

// ---------------- launch ----------------

extern "C" void kernel_launch(void* const* d_in, const int* in_sizes, int n_in,
                              void* d_out, int out_size, void* d_ws, size_t ws_size,
                              hipStream_t stream) {
    const int N = NNODES, E = NEDGES;
    const float* x   = (const float*)d_in[0];
    const int*   ei  = (const int*)d_in[1];
    const int*   src = ei;
    const int*   dst = ei + E;
    const float* W1  = (const float*)d_in[2];
    const float* b1  = (const float*)d_in[3];
    const float* Wm1 = (const float*)d_in[4];
    const float* bm1 = (const float*)d_in[5];
    const float* Wm2 = (const float*)d_in[6];
    const float* bm2 = (const float*)d_in[7];
    const float* W2  = (const float*)d_in[8];
    const float* b2  = (const float*)d_in[9];
    float* out = (float*)d_out;

    // workspace layout (all offsets multiples of 4 elems -> 16B aligned)
    int* deg     = (int*)d_ws;               // N
    int* fill    = deg + N;                  // N
    int* row_ptr = fill + N;                 // N+4 (slot)
    int* bsum    = row_ptr + (N + 4);        // 256
    int* col     = bsum + 256;               // E
    float* dinv  = (float*)(col + E);        // N
    float* t     = dinv + N;                 // N*128
    float* bufA  = t + (size_t)N * 128;      // N*128

    const int NBLK = (N + 1023) / 1024;      // 98
    const int EB   = (E + 255) / 256;

    zero_ints<<<(2 * N + 255) / 256, 256, 0, stream>>>(deg, 2 * N);
    count_deg<<<EB, 256, 0, stream>>>(dst, deg, E);
    compute_dinv<<<(N + 255) / 256, 256, 0, stream>>>(deg, dinv, N);
    scan_block_sums<<<NBLK, 256, 0, stream>>>(deg, bsum, N);
    scan_small_exclusive<<<1, 256, 0, stream>>>(bsum, NBLK, row_ptr, N, E);
    scan_write<<<NBLK, 256, 0, stream>>>(deg, bsum, row_ptr, N);
    fill_csr<<<EB, 256, 0, stream>>>(src, dst, row_ptr, fill, col, E);

    const int GB = (N + 127) / 128;          // gemm blocks
    const int AB = (N + 3) / 4;              // agg blocks (4 waves/block)

    // layer 1: x -> bufA
    gemm_k128_ps<128><<<GB, 256, 0, stream>>>(x, W1, dinv, t, N);
    agg128<true><<<AB, 256, 0, stream>>>(t, row_ptr, col, dinv, b1, bufA, N);
    // layer 2
    gemm_k128_ps<128><<<GB, 256, 0, stream>>>(bufA, Wm1, dinv, t, N);
    agg128<true><<<AB, 256, 0, stream>>>(t, row_ptr, col, dinv, bm1, bufA, N);
    // layer 3
    gemm_k128_ps<128><<<GB, 256, 0, stream>>>(bufA, Wm2, dinv, t, N);
    agg128<true><<<AB, 256, 0, stream>>>(t, row_ptr, col, dinv, bm2, bufA, N);
    // layer 4: no relu, output 64 features
    gemm_k128_ps<64><<<GB, 256, 0, stream>>>(bufA, W2, dinv, t, N);
    agg64<false><<<AB, 256, 0, stream>>>(t, row_ptr, col, dinv, b2, out, N);
}

// Round 3
// 655.999 us; speedup vs baseline: 1.7360x; 1.4749x over previous
//
#include <hip/hip_runtime.h>
#include <hip/hip_bf16.h>
#include <hip/hip_fp16.h>

// GCN 4 layers. t_pre = dinv[row]*(H @ W) via split-bf16 MFMA, stored fp16.
// out[i] = dinv[i]*(sum_{src->i} t_pre[src] + t_pre[i]) + b ; relu (not last).
// Activations fp16 between layers; final output fp32.

#define NNODES 100000
#define NEDGES 1600000

typedef __attribute__((ext_vector_type(8))) short bf16x8;
typedef __attribute__((ext_vector_type(4))) float f32x4;

// ---------------- helpers ----------------

__device__ inline float2 h2f2(unsigned int u) {
    __half2 h = *reinterpret_cast<__half2*>(&u);
    return __half22float2(h);
}
__device__ inline unsigned int f22h2(float a, float b) {
    __half2 h = __floats2half2_rn(a, b);
    return *reinterpret_cast<unsigned int*>(&h);
}

// truncation split: x = bf16(hi) + bf16(lo) + O(2^-17 x)
__device__ inline void split1(float x, short& hi, short& lo) {
    unsigned int u = __float_as_uint(x);
    hi = (short)(u >> 16);
    float r = x - __uint_as_float(u & 0xFFFF0000u);
    lo = (short)(__float_as_uint(r) >> 16);
}

__device__ inline void split8f(const float* f, bf16x8& hi, bf16x8& lo) {
#pragma unroll
    for (int i = 0; i < 8; i++) { short h, l; split1(f[i], h, l); hi[i] = h; lo[i] = l; }
}

// ---------------- CSR build ----------------

__global__ void zero_ints(int* p, int n) {
    int i = blockIdx.x * blockDim.x + threadIdx.x;
    if (i < n) p[i] = 0;
}

__global__ void count_deg(const int* __restrict__ dst, int* __restrict__ deg, int e) {
    int i = blockIdx.x * blockDim.x + threadIdx.x;
    if (i < e) atomicAdd(&deg[dst[i]], 1);
}

__global__ void compute_dinv(const int* __restrict__ deg, float* __restrict__ dinv, int n) {
    int i = blockIdx.x * blockDim.x + threadIdx.x;
    if (i < n) dinv[i] = rsqrtf((float)(deg[i] + 1));
}

__global__ void scan_block_sums(const int* __restrict__ deg, int* __restrict__ bsum, int n) {
    __shared__ int sd[256];
    int t = threadIdx.x;
    int base = blockIdx.x * 1024 + t * 4;
    int s = 0;
#pragma unroll
    for (int j = 0; j < 4; j++) { int i = base + j; if (i < n) s += deg[i]; }
    sd[t] = s; __syncthreads();
    for (int off = 128; off > 0; off >>= 1) {
        if (t < off) sd[t] += sd[t + off];
        __syncthreads();
    }
    if (t == 0) bsum[blockIdx.x] = sd[0];
}

__global__ void scan_small_exclusive(int* __restrict__ bsum, int nb,
                                     int* __restrict__ row_ptr, int n, int e) {
    __shared__ int sd[256];
    int t = threadIdx.x;
    int v = (t < nb) ? bsum[t] : 0;
    sd[t] = v; __syncthreads();
    for (int off = 1; off < 256; off <<= 1) {
        int x = (t >= off) ? sd[t - off] : 0;
        __syncthreads();
        sd[t] += x;
        __syncthreads();
    }
    if (t < nb) bsum[t] = sd[t] - v;
    if (t == 0) row_ptr[n] = e;
}

__global__ void scan_write(const int* __restrict__ deg, const int* __restrict__ bsum,
                           int* __restrict__ row_ptr, int n) {
    __shared__ int sd[256];
    int t = threadIdx.x;
    int base = blockIdx.x * 1024 + t * 4;
    int v[4]; int s = 0;
#pragma unroll
    for (int j = 0; j < 4; j++) { int i = base + j; v[j] = (i < n) ? deg[i] : 0; s += v[j]; }
    sd[t] = s; __syncthreads();
    for (int off = 1; off < 256; off <<= 1) {
        int x = (t >= off) ? sd[t - off] : 0;
        __syncthreads();
        sd[t] += x;
        __syncthreads();
    }
    int run = bsum[blockIdx.x] + (sd[t] - s);
#pragma unroll
    for (int j = 0; j < 4; j++) {
        int i = base + j;
        if (i < n) row_ptr[i] = run;
        run += v[j];
    }
}

__global__ void fill_csr(const int* __restrict__ src, const int* __restrict__ dst,
                         const int* __restrict__ row_ptr, int* __restrict__ fill,
                         int* __restrict__ col, int e) {
    int i = blockIdx.x * blockDim.x + threadIdx.x;
    if (i < e) {
        int d = dst[i];
        int o = atomicAdd(&fill[d], 1);
        col[row_ptr[d] + o] = src[i];
    }
}

// ---------------- weight -> bf16 hi/lo fragment order ----------------
// frag layout: [chunk c][tile t][lane l][j], k = c*32 + (l>>4)*8 + j, n = t*16 + (l&15)

template <int N>
__global__ void conv_wfrag(const float* __restrict__ W, unsigned short* __restrict__ hi,
                           unsigned short* __restrict__ lo) {
    constexpr int NT = N / 16;
    int e = blockIdx.x * 256 + threadIdx.x;
    if (e >= 4 * NT * 64 * 8) return;
    int j = e & 7;
    int l = (e >> 3) & 63;
    int t = (e >> 9) % NT;
    int c = e / (512 * NT);
    int k = c * 32 + (l >> 4) * 8 + j;
    int n = t * 16 + (l & 15);
    float x = W[k * N + n];
    short h, lw; split1(x, h, lw);
    hi[e] = (unsigned short)h;
    lo[e] = (unsigned short)lw;
}

// ---------------- GEMM: T(fp16) = dinv[row] * (A @ W), split-bf16 3-term MFMA ----------
// wave = 32 rows (2 x 16-row tiles) x BN cols. 4 waves/block. W frags staged in LDS.

template <typename AT, int BN>
__global__ __launch_bounds__(256) void gemm_mfma(const AT* __restrict__ A,
                                                 const unsigned short* __restrict__ gwhi,
                                                 const unsigned short* __restrict__ gwlo,
                                                 const float* __restrict__ dinv,
                                                 __half* __restrict__ T, int nrows) {
    constexpr int NT = BN / 16;
    constexpr int WFRAG = 4 * NT * 64 * 8;
    __shared__ __align__(16) unsigned short s_hi[WFRAG];
    __shared__ __align__(16) unsigned short s_lo[WFRAG];
    int tid = threadIdx.x;
    for (int i = tid; i < WFRAG / 8; i += 256) {
        ((uint4*)s_hi)[i] = ((const uint4*)gwhi)[i];
        ((uint4*)s_lo)[i] = ((const uint4*)gwlo)[i];
    }
    __syncthreads();

    int wave = tid >> 6, lane = tid & 63;
    int m = lane & 15, q = lane >> 4;
    long row0 = ((long)blockIdx.x * 4 + wave) * 32;
    if (row0 >= nrows) return;
    long rowa = row0 + m;
    bool hasb = (row0 + 16) < nrows;           // nrows % 16 == 0 -> full tiles
    long rowb = hasb ? (row0 + 16 + m) : rowa;

    f32x4 acc[2][NT];
#pragma unroll
    for (int s = 0; s < 2; s++)
#pragma unroll
        for (int t = 0; t < NT; t++)
#pragma unroll
            for (int r = 0; r < 4; r++) acc[s][t][r] = 0.f;

#pragma unroll
    for (int c = 0; c < 4; c++) {
        bf16x8 ah[2], al[2];
        float fa[8], fb[8];
        if constexpr (sizeof(AT) == 2) {
            uint4 ra = *(const uint4*)((const __half*)A + rowa * 128 + c * 32 + q * 8);
            uint4 rb = *(const uint4*)((const __half*)A + rowb * 128 + c * 32 + q * 8);
            float2 t0;
            t0 = h2f2(ra.x); fa[0] = t0.x; fa[1] = t0.y;
            t0 = h2f2(ra.y); fa[2] = t0.x; fa[3] = t0.y;
            t0 = h2f2(ra.z); fa[4] = t0.x; fa[5] = t0.y;
            t0 = h2f2(ra.w); fa[6] = t0.x; fa[7] = t0.y;
            t0 = h2f2(rb.x); fb[0] = t0.x; fb[1] = t0.y;
            t0 = h2f2(rb.y); fb[2] = t0.x; fb[3] = t0.y;
            t0 = h2f2(rb.z); fb[4] = t0.x; fb[5] = t0.y;
            t0 = h2f2(rb.w); fb[6] = t0.x; fb[7] = t0.y;
        } else {
            const float* pa = (const float*)A + rowa * 128 + c * 32 + q * 8;
            const float* pb = (const float*)A + rowb * 128 + c * 32 + q * 8;
            *(float4*)&fa[0] = *(const float4*)pa;
            *(float4*)&fa[4] = *(const float4*)(pa + 4);
            *(float4*)&fb[0] = *(const float4*)pb;
            *(float4*)&fb[4] = *(const float4*)(pb + 4);
        }
        split8f(fa, ah[0], al[0]);
        split8f(fb, ah[1], al[1]);

#pragma unroll
        for (int t = 0; t < NT; t++) {
            bf16x8 bhi = *(const bf16x8*)(s_hi + ((c * NT + t) * 64 + lane) * 8);
            bf16x8 blo = *(const bf16x8*)(s_lo + ((c * NT + t) * 64 + lane) * 8);
#pragma unroll
            for (int s = 0; s < 2; s++) {
                acc[s][t] = __builtin_amdgcn_mfma_f32_16x16x32_bf16(al[s], bhi, acc[s][t], 0, 0, 0);
                acc[s][t] = __builtin_amdgcn_mfma_f32_16x16x32_bf16(ah[s], blo, acc[s][t], 0, 0, 0);
                acc[s][t] = __builtin_amdgcn_mfma_f32_16x16x32_bf16(ah[s], bhi, acc[s][t], 0, 0, 0);
            }
        }
    }

    // epilogue: C/D layout col = lane&15, row = q*4 + r
#pragma unroll
    for (int s = 0; s < 2; s++) {
        if (s == 1 && !hasb) break;
#pragma unroll
        for (int r = 0; r < 4; r++) {
            long row = row0 + s * 16 + q * 4 + r;
            if (row < nrows) {
                float di = dinv[row];
#pragma unroll
                for (int t = 0; t < NT; t++)
                    T[row * BN + t * 16 + m] = __float2half(acc[s][t][r] * di);
            }
        }
    }
}

// ---------------- aggregation: wave per node, quarter-wave per neighbor row ------------
// F=128 fp16: row = 256 B = 16 lanes x 16 B. lane (q,i): q = edge slot, i = chunk.

__device__ inline void acc8(float* a, uint4 v) {
    float2 f0 = h2f2(v.x), f1 = h2f2(v.y), f2 = h2f2(v.z), f3 = h2f2(v.w);
    a[0] += f0.x; a[1] += f0.y; a[2] += f1.x; a[3] += f1.y;
    a[4] += f2.x; a[5] += f2.y; a[6] += f3.x; a[7] += f3.y;
}
__device__ inline void acc4(float* a, uint2 v) {
    float2 f0 = h2f2(v.x), f1 = h2f2(v.y);
    a[0] += f0.x; a[1] += f0.y; a[2] += f1.x; a[3] += f1.y;
}

__global__ __launch_bounds__(256) void agg128h(const __half* __restrict__ t,
                                               const int* __restrict__ row_ptr,
                                               const int* __restrict__ col,
                                               const float* __restrict__ dinv,
                                               const float* __restrict__ bias,
                                               __half* __restrict__ out, int n) {
    int wave = threadIdx.x >> 6, lane = threadIdx.x & 63;
    int node = blockIdx.x * 4 + wave;
    if (node >= n) return;
    int q = lane >> 4, i = lane & 15;
    int r0 = row_ptr[node], r1 = row_ptr[node + 1];
    const uint4* t4 = (const uint4*)t;

    float a0[8], a1[8], a2[8], a3[8];
#pragma unroll
    for (int k = 0; k < 8; k++) { a0[k] = 0.f; a1[k] = 0.f; a2[k] = 0.f; a3[k] = 0.f; }

    int p = r0;
    for (; p + 16 <= r1; p += 16) {
        int c0 = col[p + q];
        int c1 = col[p + 4 + q];
        int c2 = col[p + 8 + q];
        int c3 = col[p + 12 + q];
        uint4 v0 = t4[(size_t)c0 * 16 + i];
        uint4 v1 = t4[(size_t)c1 * 16 + i];
        uint4 v2 = t4[(size_t)c2 * 16 + i];
        uint4 v3 = t4[(size_t)c3 * 16 + i];
        acc8(a0, v0); acc8(a1, v1); acc8(a2, v2); acc8(a3, v3);
    }
    for (; p + 8 <= r1; p += 8) {
        int c0 = col[p + q];
        int c1 = col[p + 4 + q];
        uint4 v0 = t4[(size_t)c0 * 16 + i];
        uint4 v1 = t4[(size_t)c1 * 16 + i];
        acc8(a0, v0); acc8(a1, v1);
    }
    for (; p < r1; p += 4) {
        int idx = p + q;
        if (idx < r1) {
            int c = col[idx];
            acc8(a0, t4[(size_t)c * 16 + i]);
        }
    }

    float s[8];
#pragma unroll
    for (int k = 0; k < 8; k++) s[k] = (a0[k] + a1[k]) + (a2[k] + a3[k]);
#pragma unroll
    for (int k = 0; k < 8; k++) s[k] += __shfl_xor(s[k], 16);
#pragma unroll
    for (int k = 0; k < 8; k++) s[k] += __shfl_xor(s[k], 32);

    if (q == 0) {
        uint4 ownv = t4[(size_t)node * 16 + i];
        float own[8];
        float2 f0 = h2f2(ownv.x), f1 = h2f2(ownv.y), f2 = h2f2(ownv.z), f3 = h2f2(ownv.w);
        own[0] = f0.x; own[1] = f0.y; own[2] = f1.x; own[3] = f1.y;
        own[4] = f2.x; own[5] = f2.y; own[6] = f3.x; own[7] = f3.y;
        float di = dinv[node];
        float4 bA = ((const float4*)bias)[i * 2];
        float4 bB = ((const float4*)bias)[i * 2 + 1];
        float o[8];
        o[0] = di * (s[0] + own[0]) + bA.x;
        o[1] = di * (s[1] + own[1]) + bA.y;
        o[2] = di * (s[2] + own[2]) + bA.z;
        o[3] = di * (s[3] + own[3]) + bA.w;
        o[4] = di * (s[4] + own[4]) + bB.x;
        o[5] = di * (s[5] + own[5]) + bB.y;
        o[6] = di * (s[6] + own[6]) + bB.z;
        o[7] = di * (s[7] + own[7]) + bB.w;
#pragma unroll
        for (int k = 0; k < 8; k++) o[k] = fmaxf(o[k], 0.f);   // all 128-wide layers have relu
        uint4 ov;
        ov.x = f22h2(o[0], o[1]); ov.y = f22h2(o[2], o[3]);
        ov.z = f22h2(o[4], o[5]); ov.w = f22h2(o[6], o[7]);
        ((uint4*)out)[(size_t)node * 16 + i] = ov;
    }
}

// F=64 fp16 table, fp32 output, no relu. row = 128 B = 16 lanes x 8 B.
__global__ __launch_bounds__(256) void agg64h(const __half* __restrict__ t,
                                              const int* __restrict__ row_ptr,
                                              const int* __restrict__ col,
                                              const float* __restrict__ dinv,
                                              const float* __restrict__ bias,
                                              float* __restrict__ out, int n) {
    int wave = threadIdx.x >> 6, lane = threadIdx.x & 63;
    int node = blockIdx.x * 4 + wave;
    if (node >= n) return;
    int q = lane >> 4, i = lane & 15;
    int r0 = row_ptr[node], r1 = row_ptr[node + 1];
    const uint2* t2 = (const uint2*)t;

    float a0[4], a1[4], a2[4], a3[4];
#pragma unroll
    for (int k = 0; k < 4; k++) { a0[k] = 0.f; a1[k] = 0.f; a2[k] = 0.f; a3[k] = 0.f; }

    int p = r0;
    for (; p + 16 <= r1; p += 16) {
        int c0 = col[p + q];
        int c1 = col[p + 4 + q];
        int c2 = col[p + 8 + q];
        int c3 = col[p + 12 + q];
        uint2 v0 = t2[(size_t)c0 * 16 + i];
        uint2 v1 = t2[(size_t)c1 * 16 + i];
        uint2 v2 = t2[(size_t)c2 * 16 + i];
        uint2 v3 = t2[(size_t)c3 * 16 + i];
        acc4(a0, v0); acc4(a1, v1); acc4(a2, v2); acc4(a3, v3);
    }
    for (; p + 8 <= r1; p += 8) {
        int c0 = col[p + q];
        int c1 = col[p + 4 + q];
        uint2 v0 = t2[(size_t)c0 * 16 + i];
        uint2 v1 = t2[(size_t)c1 * 16 + i];
        acc4(a0, v0); acc4(a1, v1);
    }
    for (; p < r1; p += 4) {
        int idx = p + q;
        if (idx < r1) {
            int c = col[idx];
            acc4(a0, t2[(size_t)c * 16 + i]);
        }
    }

    float s[4];
#pragma unroll
    for (int k = 0; k < 4; k++) s[k] = (a0[k] + a1[k]) + (a2[k] + a3[k]);
#pragma unroll
    for (int k = 0; k < 4; k++) s[k] += __shfl_xor(s[k], 16);
#pragma unroll
    for (int k = 0; k < 4; k++) s[k] += __shfl_xor(s[k], 32);

    if (q == 0) {
        uint2 ownv = t2[(size_t)node * 16 + i];
        float own[4];
        float2 f0 = h2f2(ownv.x), f1 = h2f2(ownv.y);
        own[0] = f0.x; own[1] = f0.y; own[2] = f1.x; own[3] = f1.y;
        float di = dinv[node];
        float4 b4 = ((const float4*)bias)[i];
        float4 o;
        o.x = di * (s[0] + own[0]) + b4.x;
        o.y = di * (s[1] + own[1]) + b4.y;
        o.z = di * (s[2] + own[2]) + b4.z;
        o.w = di * (s[3] + own[3]) + b4.w;
        ((float4*)out)[(size_t)node * 16 + i] = o;
    }
}

// ---------------- launch ----------------

extern "C" void kernel_launch(void* const* d_in, const int* in_sizes, int n_in,
                              void* d_out, int out_size, void* d_ws, size_t ws_size,
                              hipStream_t stream) {
    const int N = NNODES, E = NEDGES;
    const float* x   = (const float*)d_in[0];
    const int*   ei  = (const int*)d_in[1];
    const int*   src = ei;
    const int*   dst = ei + E;
    const float* W1  = (const float*)d_in[2];
    const float* b1  = (const float*)d_in[3];
    const float* Wm1 = (const float*)d_in[4];
    const float* bm1 = (const float*)d_in[5];
    const float* Wm2 = (const float*)d_in[6];
    const float* bm2 = (const float*)d_in[7];
    const float* W2  = (const float*)d_in[8];
    const float* b2  = (const float*)d_in[9];
    float* out = (float*)d_out;

    // workspace layout
    int* deg     = (int*)d_ws;               // N
    int* fill    = deg + N;                  // N
    int* row_ptr = fill + N;                 // N+4
    int* bsum    = row_ptr + (N + 4);        // 256
    int* col     = bsum + 256;               // E
    float* dinv  = (float*)(col + E);        // N
    __half* t16  = (__half*)(dinv + N);      // N*128 halves
    __half* bufA = t16 + (size_t)N * 128;    // N*128 halves
    unsigned short* whi1  = (unsigned short*)(bufA + (size_t)N * 128);
    unsigned short* wlo1  = whi1 + 16384;
    unsigned short* whiM1 = wlo1 + 16384;
    unsigned short* wloM1 = whiM1 + 16384;
    unsigned short* whiM2 = wloM1 + 16384;
    unsigned short* wloM2 = whiM2 + 16384;
    unsigned short* whi2  = wloM2 + 16384;
    unsigned short* wlo2  = whi2 + 8192;

    const int NBLK = (N + 1023) / 1024;
    const int EB   = (E + 255) / 256;

    zero_ints<<<(2 * N + 255) / 256, 256, 0, stream>>>(deg, 2 * N);
    count_deg<<<EB, 256, 0, stream>>>(dst, deg, E);
    compute_dinv<<<(N + 255) / 256, 256, 0, stream>>>(deg, dinv, N);
    scan_block_sums<<<NBLK, 256, 0, stream>>>(deg, bsum, N);
    scan_small_exclusive<<<1, 256, 0, stream>>>(bsum, NBLK, row_ptr, N, E);
    scan_write<<<NBLK, 256, 0, stream>>>(deg, bsum, row_ptr, N);
    fill_csr<<<EB, 256, 0, stream>>>(src, dst, row_ptr, fill, col, E);

    conv_wfrag<128><<<64, 256, 0, stream>>>(W1, whi1, wlo1);
    conv_wfrag<128><<<64, 256, 0, stream>>>(Wm1, whiM1, wloM1);
    conv_wfrag<128><<<64, 256, 0, stream>>>(Wm2, whiM2, wloM2);
    conv_wfrag<64><<<32, 256, 0, stream>>>(W2, whi2, wlo2);

    const int GB = (N + 127) / 128;          // 32 rows/wave * 4 waves
    const int AB = (N + 3) / 4;

    gemm_mfma<float, 128><<<GB, 256, 0, stream>>>(x, whi1, wlo1, dinv, t16, N);
    agg128h<<<AB, 256, 0, stream>>>(t16, row_ptr, col, dinv, b1, bufA, N);

    gemm_mfma<__half, 128><<<GB, 256, 0, stream>>>(bufA, whiM1, wloM1, dinv, t16, N);
    agg128h<<<AB, 256, 0, stream>>>(t16, row_ptr, col, dinv, bm1, bufA, N);

    gemm_mfma<__half, 128><<<GB, 256, 0, stream>>>(bufA, whiM2, wloM2, dinv, t16, N);
    agg128h<<<AB, 256, 0, stream>>>(t16, row_ptr, col, dinv, bm2, bufA, N);

    gemm_mfma<__half, 64><<<GB, 256, 0, stream>>>(bufA, whi2, wlo2, dinv, t16, N);
    agg64h<<<AB, 256, 0, stream>>>(t16, row_ptr, col, dinv, b2, out, N);
}

// Round 4
// 557.329 us; speedup vs baseline: 2.0434x; 1.1770x over previous
//
#include <hip/hip_runtime.h>
#include <hip/hip_bf16.h>
#include <hip/hip_fp16.h>

// GCN 4 layers. t_pre = dinv[row]*(H @ W) via split-bf16 MFMA, stored fp16.
// out[i] = dinv[i]*(sum_{src->i} t_pre[src] + t_pre[i]) + b ; relu (not last).
// CSR built per call via bucket partition (dst>>7), avoiding 64B-line scatter blowup.

#define NNODES 100000
#define NEDGES 1600000
#define NBUCK 782          // ceil(N/128)

typedef __attribute__((ext_vector_type(8))) short bf16x8;
typedef __attribute__((ext_vector_type(4))) float f32x4;

// ---------------- helpers ----------------

__device__ inline float2 h2f2(unsigned int u) {
    __half2 h = *reinterpret_cast<__half2*>(&u);
    return __half22float2(h);
}
__device__ inline unsigned int f22h2(float a, float b) {
    __half2 h = __floats2half2_rn(a, b);
    return *reinterpret_cast<unsigned int*>(&h);
}

// truncation split: x = bf16(hi) + bf16(lo) + O(2^-17 x)
__device__ inline void split1(float x, short& hi, short& lo) {
    unsigned int u = __float_as_uint(x);
    hi = (short)(u >> 16);
    float r = x - __uint_as_float(u & 0xFFFF0000u);
    lo = (short)(__float_as_uint(r) >> 16);
}

__device__ inline void split8f(const float* f, bf16x8& hi, bf16x8& lo) {
#pragma unroll
    for (int i = 0; i < 8; i++) { short h, l; split1(f[i], h, l); hi[i] = h; lo[i] = l; }
}

// ---------------- bucket-partition CSR build ----------------

__global__ void zero_ints(int* p, int n) {
    int i = blockIdx.x * blockDim.x + threadIdx.x;
    if (i < n) p[i] = 0;
}

// pass 1: per-chunk LDS histogram -> global bucket counts. chunk = 4096 edges.
__global__ __launch_bounds__(256) void hist_pass(const int* __restrict__ dst,
                                                 int* __restrict__ cnt, int e) {
    __shared__ int h[NBUCK];
    int tid = threadIdx.x;
    for (int i = tid; i < NBUCK; i += 256) h[i] = 0;
    __syncthreads();
    int base_e = blockIdx.x * 4096;
#pragma unroll
    for (int j = 0; j < 16; j++) {
        int i = base_e + j * 256 + tid;
        if (i < e) atomicAdd(&h[dst[i] >> 7], 1);
    }
    __syncthreads();
    for (int b = tid; b < NBUCK; b += 256)
        if (h[b]) atomicAdd(&cnt[b], h[b]);
}

// exclusive scan of 782 bucket counts (single block).
__global__ __launch_bounds__(256) void scan_buckets(const int* __restrict__ cnt,
                                                    int* __restrict__ base,
                                                    int* __restrict__ fill, int e) {
    __shared__ int sd[256];
    int t = threadIdx.x;
    int v[4]; int s = 0;
#pragma unroll
    for (int j = 0; j < 4; j++) {
        int i = t * 4 + j;
        v[j] = (i < NBUCK) ? cnt[i] : 0;
        s += v[j];
    }
    sd[t] = s; __syncthreads();
    for (int off = 1; off < 256; off <<= 1) {
        int x = (t >= off) ? sd[t - off] : 0;
        __syncthreads();
        sd[t] += x;
        __syncthreads();
    }
    int run = sd[t] - s;   // exclusive
#pragma unroll
    for (int j = 0; j < 4; j++) {
        int i = t * 4 + j;
        if (i < NBUCK) { base[i] = run; fill[i] = run; }
        run += v[j];
    }
    if (t == 0) base[NBUCK] = e;
}

// pass 2: re-histogram per chunk, reserve ranges, scatter packed (src<<7)|(dst&127).
__global__ __launch_bounds__(256) void scatter_pass(const int* __restrict__ src,
                                                    const int* __restrict__ dst,
                                                    int* __restrict__ fill,
                                                    unsigned int* __restrict__ epart, int e) {
    __shared__ int h[NBUCK];
    int tid = threadIdx.x;
    for (int i = tid; i < NBUCK; i += 256) h[i] = 0;
    __syncthreads();
    int base_e = blockIdx.x * 4096;
#pragma unroll
    for (int j = 0; j < 16; j++) {
        int i = base_e + j * 256 + tid;
        if (i < e) atomicAdd(&h[dst[i] >> 7], 1);
    }
    __syncthreads();
    for (int b = tid; b < NBUCK; b += 256)
        if (h[b]) h[b] = atomicAdd(&fill[b], h[b]);
    __syncthreads();
#pragma unroll
    for (int j = 0; j < 16; j++) {
        int i = base_e + j * 256 + tid;
        if (i < e) {
            int d = dst[i];
            int bk = d >> 7;
            int pos = atomicAdd(&h[bk], 1);
            epart[pos] = ((unsigned int)src[i] << 7) | (unsigned int)(d & 127);
        }
    }
}

// pass 3: block per bucket -> row_ptr, dinv, col (writes stay in bucket's ~8KB region).
__global__ __launch_bounds__(256) void build_csr(const unsigned int* __restrict__ epart,
                                                 const int* __restrict__ base,
                                                 int* __restrict__ row_ptr,
                                                 int* __restrict__ col,
                                                 float* __restrict__ dinv,
                                                 int n, int e_total) {
    __shared__ int deg[128], off[128], fil[128];
    int b = blockIdx.x, tid = threadIdx.x;
    int node0 = b << 7;
    int nn = n - node0; if (nn > 128) nn = 128;
    int e0 = base[b], e1 = base[b + 1];
    int cnt = e1 - e0;

    if (tid < 128) deg[tid] = 0;
    __syncthreads();
    for (int i = tid; i < cnt; i += 256)
        atomicAdd(&deg[epart[e0 + i] & 127], 1);
    __syncthreads();
    if (tid < 128) off[tid] = deg[tid];
    __syncthreads();
    for (int o = 1; o < 128; o <<= 1) {
        int x = (tid < 128 && tid >= o) ? off[tid - o] : 0;
        __syncthreads();
        if (tid < 128) off[tid] += x;
        __syncthreads();
    }
    if (tid < nn) {
        int ex = e0 + off[tid] - deg[tid];
        row_ptr[node0 + tid] = ex;
        fil[tid] = ex;
        dinv[node0 + tid] = rsqrtf((float)(deg[tid] + 1));
    }
    if (b == 0 && tid == 0) row_ptr[n] = e_total;
    __syncthreads();
    for (int i = tid; i < cnt; i += 256) {
        unsigned int u = epart[e0 + i];
        int ld = (int)(u & 127);
        int pos = atomicAdd(&fil[ld], 1);
        col[pos] = (int)(u >> 7);
    }
}

// ---------------- weight -> bf16 hi/lo fragment order (all 4 weights, one launch) -----
// frag layout: [chunk c][tile t][lane l][j], k = c*32 + (l>>4)*8 + j, n = t*16 + (l&15)

__device__ inline void wfrag_one(const float* W, unsigned short* hi, unsigned short* lo,
                                 int e, int NT, int Ncols) {
    int j = e & 7;
    int l = (e >> 3) & 63;
    int t = (e >> 9) % NT;
    int c = e / (512 * NT);
    int k = c * 32 + (l >> 4) * 8 + j;
    int n = t * 16 + (l & 15);
    float x = W[k * Ncols + n];
    short h, lw; split1(x, h, lw);
    hi[e] = (unsigned short)h;
    lo[e] = (unsigned short)lw;
}

__global__ void conv_all(const float* W1, unsigned short* hi1, unsigned short* lo1,
                         const float* Wm1, unsigned short* him1, unsigned short* lom1,
                         const float* Wm2, unsigned short* him2, unsigned short* lom2,
                         const float* W2, unsigned short* hi2, unsigned short* lo2) {
    int blk = blockIdx.x;
    int tid = threadIdx.x;
    if (blk < 64)        wfrag_one(W1,  hi1,  lo1,  blk * 256 + tid,        8, 128);
    else if (blk < 128)  wfrag_one(Wm1, him1, lom1, (blk - 64) * 256 + tid, 8, 128);
    else if (blk < 192)  wfrag_one(Wm2, him2, lom2, (blk - 128) * 256 + tid, 8, 128);
    else                 wfrag_one(W2,  hi2,  lo2,  (blk - 192) * 256 + tid, 4, 64);
}

// ---------------- GEMM: T(fp16) = dinv[row] * (A @ W), split-bf16 3-term MFMA ----------

template <typename AT, int BN>
__global__ __launch_bounds__(256) void gemm_mfma(const AT* __restrict__ A,
                                                 const unsigned short* __restrict__ gwhi,
                                                 const unsigned short* __restrict__ gwlo,
                                                 const float* __restrict__ dinv,
                                                 __half* __restrict__ T, int nrows) {
    constexpr int NT = BN / 16;
    constexpr int WFRAG = 4 * NT * 64 * 8;
    __shared__ __align__(16) unsigned short s_hi[WFRAG];
    __shared__ __align__(16) unsigned short s_lo[WFRAG];
    int tid = threadIdx.x;
    for (int i = tid; i < WFRAG / 8; i += 256) {
        ((uint4*)s_hi)[i] = ((const uint4*)gwhi)[i];
        ((uint4*)s_lo)[i] = ((const uint4*)gwlo)[i];
    }
    __syncthreads();

    int wave = tid >> 6, lane = tid & 63;
    int m = lane & 15, q = lane >> 4;
    long row0 = ((long)blockIdx.x * 4 + wave) * 32;
    if (row0 >= nrows) return;
    long rowa = row0 + m;
    bool hasb = (row0 + 16) < nrows;
    long rowb = hasb ? (row0 + 16 + m) : rowa;

    f32x4 acc[2][NT];
#pragma unroll
    for (int s = 0; s < 2; s++)
#pragma unroll
        for (int t = 0; t < NT; t++)
#pragma unroll
            for (int r = 0; r < 4; r++) acc[s][t][r] = 0.f;

#pragma unroll
    for (int c = 0; c < 4; c++) {
        bf16x8 ah[2], al[2];
        float fa[8], fb[8];
        if constexpr (sizeof(AT) == 2) {
            uint4 ra = *(const uint4*)((const __half*)A + rowa * 128 + c * 32 + q * 8);
            uint4 rb = *(const uint4*)((const __half*)A + rowb * 128 + c * 32 + q * 8);
            float2 t0;
            t0 = h2f2(ra.x); fa[0] = t0.x; fa[1] = t0.y;
            t0 = h2f2(ra.y); fa[2] = t0.x; fa[3] = t0.y;
            t0 = h2f2(ra.z); fa[4] = t0.x; fa[5] = t0.y;
            t0 = h2f2(ra.w); fa[6] = t0.x; fa[7] = t0.y;
            t0 = h2f2(rb.x); fb[0] = t0.x; fb[1] = t0.y;
            t0 = h2f2(rb.y); fb[2] = t0.x; fb[3] = t0.y;
            t0 = h2f2(rb.z); fb[4] = t0.x; fb[5] = t0.y;
            t0 = h2f2(rb.w); fb[6] = t0.x; fb[7] = t0.y;
        } else {
            const float* pa = (const float*)A + rowa * 128 + c * 32 + q * 8;
            const float* pb = (const float*)A + rowb * 128 + c * 32 + q * 8;
            *(float4*)&fa[0] = *(const float4*)pa;
            *(float4*)&fa[4] = *(const float4*)(pa + 4);
            *(float4*)&fb[0] = *(const float4*)pb;
            *(float4*)&fb[4] = *(const float4*)(pb + 4);
        }
        split8f(fa, ah[0], al[0]);
        split8f(fb, ah[1], al[1]);

#pragma unroll
        for (int t = 0; t < NT; t++) {
            bf16x8 bhi = *(const bf16x8*)(s_hi + ((c * NT + t) * 64 + lane) * 8);
            bf16x8 blo = *(const bf16x8*)(s_lo + ((c * NT + t) * 64 + lane) * 8);
#pragma unroll
            for (int s = 0; s < 2; s++) {
                acc[s][t] = __builtin_amdgcn_mfma_f32_16x16x32_bf16(al[s], bhi, acc[s][t], 0, 0, 0);
                acc[s][t] = __builtin_amdgcn_mfma_f32_16x16x32_bf16(ah[s], blo, acc[s][t], 0, 0, 0);
                acc[s][t] = __builtin_amdgcn_mfma_f32_16x16x32_bf16(ah[s], bhi, acc[s][t], 0, 0, 0);
            }
        }
    }

    // epilogue: C/D layout col = lane&15, row = q*4 + r
#pragma unroll
    for (int s = 0; s < 2; s++) {
        if (s == 1 && !hasb) break;
#pragma unroll
        for (int r = 0; r < 4; r++) {
            long row = row0 + s * 16 + q * 4 + r;
            if (row < nrows) {
                float di = dinv[row];
#pragma unroll
                for (int t = 0; t < NT; t++)
                    T[row * BN + t * 16 + m] = __float2half(acc[s][t][r] * di);
            }
        }
    }
}

// ---------------- aggregation: wave per node, quarter-wave per neighbor row ------------

__device__ inline void acc8(float* a, uint4 v) {
    float2 f0 = h2f2(v.x), f1 = h2f2(v.y), f2 = h2f2(v.z), f3 = h2f2(v.w);
    a[0] += f0.x; a[1] += f0.y; a[2] += f1.x; a[3] += f1.y;
    a[4] += f2.x; a[5] += f2.y; a[6] += f3.x; a[7] += f3.y;
}
__device__ inline void acc4(float* a, uint2 v) {
    float2 f0 = h2f2(v.x), f1 = h2f2(v.y);
    a[0] += f0.x; a[1] += f0.y; a[2] += f1.x; a[3] += f1.y;
}

__global__ __launch_bounds__(256) void agg128h(const __half* __restrict__ t,
                                               const int* __restrict__ row_ptr,
                                               const int* __restrict__ col,
                                               const float* __restrict__ dinv,
                                               const float* __restrict__ bias,
                                               __half* __restrict__ out, int n) {
    int wave = threadIdx.x >> 6, lane = threadIdx.x & 63;
    int node = blockIdx.x * 4 + wave;
    if (node >= n) return;
    int q = lane >> 4, i = lane & 15;
    int r0 = row_ptr[node], r1 = row_ptr[node + 1];
    const uint4* t4 = (const uint4*)t;

    float a0[8], a1[8], a2[8], a3[8];
#pragma unroll
    for (int k = 0; k < 8; k++) { a0[k] = 0.f; a1[k] = 0.f; a2[k] = 0.f; a3[k] = 0.f; }

    int p = r0;
    for (; p + 16 <= r1; p += 16) {
        int c0 = col[p + q];
        int c1 = col[p + 4 + q];
        int c2 = col[p + 8 + q];
        int c3 = col[p + 12 + q];
        uint4 v0 = t4[(size_t)c0 * 16 + i];
        uint4 v1 = t4[(size_t)c1 * 16 + i];
        uint4 v2 = t4[(size_t)c2 * 16 + i];
        uint4 v3 = t4[(size_t)c3 * 16 + i];
        acc8(a0, v0); acc8(a1, v1); acc8(a2, v2); acc8(a3, v3);
    }
    for (; p + 8 <= r1; p += 8) {
        int c0 = col[p + q];
        int c1 = col[p + 4 + q];
        uint4 v0 = t4[(size_t)c0 * 16 + i];
        uint4 v1 = t4[(size_t)c1 * 16 + i];
        acc8(a0, v0); acc8(a1, v1);
    }
    for (; p < r1; p += 4) {
        int idx = p + q;
        if (idx < r1) {
            int c = col[idx];
            acc8(a0, t4[(size_t)c * 16 + i]);
        }
    }

    float s[8];
#pragma unroll
    for (int k = 0; k < 8; k++) s[k] = (a0[k] + a1[k]) + (a2[k] + a3[k]);
#pragma unroll
    for (int k = 0; k < 8; k++) s[k] += __shfl_xor(s[k], 16);
#pragma unroll
    for (int k = 0; k < 8; k++) s[k] += __shfl_xor(s[k], 32);

    if (q == 0) {
        uint4 ownv = t4[(size_t)node * 16 + i];
        float own[8];
        float2 f0 = h2f2(ownv.x), f1 = h2f2(ownv.y), f2 = h2f2(ownv.z), f3 = h2f2(ownv.w);
        own[0] = f0.x; own[1] = f0.y; own[2] = f1.x; own[3] = f1.y;
        own[4] = f2.x; own[5] = f2.y; own[6] = f3.x; own[7] = f3.y;
        float di = dinv[node];
        float4 bA = ((const float4*)bias)[i * 2];
        float4 bB = ((const float4*)bias)[i * 2 + 1];
        float o[8];
        o[0] = di * (s[0] + own[0]) + bA.x;
        o[1] = di * (s[1] + own[1]) + bA.y;
        o[2] = di * (s[2] + own[2]) + bA.z;
        o[3] = di * (s[3] + own[3]) + bA.w;
        o[4] = di * (s[4] + own[4]) + bB.x;
        o[5] = di * (s[5] + own[5]) + bB.y;
        o[6] = di * (s[6] + own[6]) + bB.z;
        o[7] = di * (s[7] + own[7]) + bB.w;
#pragma unroll
        for (int k = 0; k < 8; k++) o[k] = fmaxf(o[k], 0.f);
        uint4 ov;
        ov.x = f22h2(o[0], o[1]); ov.y = f22h2(o[2], o[3]);
        ov.z = f22h2(o[4], o[5]); ov.w = f22h2(o[6], o[7]);
        ((uint4*)out)[(size_t)node * 16 + i] = ov;
    }
}

__global__ __launch_bounds__(256) void agg64h(const __half* __restrict__ t,
                                              const int* __restrict__ row_ptr,
                                              const int* __restrict__ col,
                                              const float* __restrict__ dinv,
                                              const float* __restrict__ bias,
                                              float* __restrict__ out, int n) {
    int wave = threadIdx.x >> 6, lane = threadIdx.x & 63;
    int node = blockIdx.x * 4 + wave;
    if (node >= n) return;
    int q = lane >> 4, i = lane & 15;
    int r0 = row_ptr[node], r1 = row_ptr[node + 1];
    const uint2* t2 = (const uint2*)t;

    float a0[4], a1[4], a2[4], a3[4];
#pragma unroll
    for (int k = 0; k < 4; k++) { a0[k] = 0.f; a1[k] = 0.f; a2[k] = 0.f; a3[k] = 0.f; }

    int p = r0;
    for (; p + 16 <= r1; p += 16) {
        int c0 = col[p + q];
        int c1 = col[p + 4 + q];
        int c2 = col[p + 8 + q];
        int c3 = col[p + 12 + q];
        uint2 v0 = t2[(size_t)c0 * 16 + i];
        uint2 v1 = t2[(size_t)c1 * 16 + i];
        uint2 v2 = t2[(size_t)c2 * 16 + i];
        uint2 v3 = t2[(size_t)c3 * 16 + i];
        acc4(a0, v0); acc4(a1, v1); acc4(a2, v2); acc4(a3, v3);
    }
    for (; p + 8 <= r1; p += 8) {
        int c0 = col[p + q];
        int c1 = col[p + 4 + q];
        uint2 v0 = t2[(size_t)c0 * 16 + i];
        uint2 v1 = t2[(size_t)c1 * 16 + i];
        acc4(a0, v0); acc4(a1, v1);
    }
    for (; p < r1; p += 4) {
        int idx = p + q;
        if (idx < r1) {
            int c = col[idx];
            acc4(a0, t2[(size_t)c * 16 + i]);
        }
    }

    float s[4];
#pragma unroll
    for (int k = 0; k < 4; k++) s[k] = (a0[k] + a1[k]) + (a2[k] + a3[k]);
#pragma unroll
    for (int k = 0; k < 4; k++) s[k] += __shfl_xor(s[k], 16);
#pragma unroll
    for (int k = 0; k < 4; k++) s[k] += __shfl_xor(s[k], 32);

    if (q == 0) {
        uint2 ownv = t2[(size_t)node * 16 + i];
        float own[4];
        float2 f0 = h2f2(ownv.x), f1 = h2f2(ownv.y);
        own[0] = f0.x; own[1] = f0.y; own[2] = f1.x; own[3] = f1.y;
        float di = dinv[node];
        float4 b4 = ((const float4*)bias)[i];
        float4 o;
        o.x = di * (s[0] + own[0]) + b4.x;
        o.y = di * (s[1] + own[1]) + b4.y;
        o.z = di * (s[2] + own[2]) + b4.z;
        o.w = di * (s[3] + own[3]) + b4.w;
        ((float4*)out)[(size_t)node * 16 + i] = o;
    }
}

// ---------------- launch ----------------

extern "C" void kernel_launch(void* const* d_in, const int* in_sizes, int n_in,
                              void* d_out, int out_size, void* d_ws, size_t ws_size,
                              hipStream_t stream) {
    const int N = NNODES, E = NEDGES;
    const float* x   = (const float*)d_in[0];
    const int*   ei  = (const int*)d_in[1];
    const int*   src = ei;
    const int*   dst = ei + E;
    const float* W1  = (const float*)d_in[2];
    const float* b1  = (const float*)d_in[3];
    const float* Wm1 = (const float*)d_in[4];
    const float* bm1 = (const float*)d_in[5];
    const float* Wm2 = (const float*)d_in[6];
    const float* bm2 = (const float*)d_in[7];
    const float* W2  = (const float*)d_in[8];
    const float* b2  = (const float*)d_in[9];
    float* out = (float*)d_out;

    // workspace layout (16B-aligned segments)
    int* bucket_cnt  = (int*)d_ws;                        // 784
    int* bucket_base = bucket_cnt + 784;                  // 784 (NBUCK+1 used)
    int* bucket_fill = bucket_base + 784;                 // 784
    int* row_ptr     = bucket_fill + 784;                 // N+4
    int* col         = row_ptr + (N + 4);                 // E
    unsigned int* epart = (unsigned int*)(col + E);       // E
    float* dinv  = (float*)(epart + E);                   // N
    __half* t16  = (__half*)(dinv + N);                   // N*128 halves
    __half* bufA = t16 + (size_t)N * 128;                 // N*128 halves
    unsigned short* whi1  = (unsigned short*)(bufA + (size_t)N * 128);
    unsigned short* wlo1  = whi1 + 16384;
    unsigned short* whiM1 = wlo1 + 16384;
    unsigned short* wloM1 = whiM1 + 16384;
    unsigned short* whiM2 = wloM1 + 16384;
    unsigned short* wloM2 = whiM2 + 16384;
    unsigned short* whi2  = wloM2 + 16384;
    unsigned short* wlo2  = whi2 + 8192;

    const int EB4 = (E + 4095) / 4096;   // 391

    zero_ints<<<4, 256, 0, stream>>>(bucket_cnt, NBUCK);
    hist_pass<<<EB4, 256, 0, stream>>>(dst, bucket_cnt, E);
    scan_buckets<<<1, 256, 0, stream>>>(bucket_cnt, bucket_base, bucket_fill, E);
    scatter_pass<<<EB4, 256, 0, stream>>>(src, dst, bucket_fill, epart, E);
    build_csr<<<NBUCK, 256, 0, stream>>>(epart, bucket_base, row_ptr, col, dinv, N, E);

    conv_all<<<224, 256, 0, stream>>>(W1, whi1, wlo1, Wm1, whiM1, wloM1,
                                      Wm2, whiM2, wloM2, W2, whi2, wlo2);

    const int GB = (N + 127) / 128;      // 32 rows/wave * 4 waves
    const int AB = (N + 3) / 4;

    gemm_mfma<float, 128><<<GB, 256, 0, stream>>>(x, whi1, wlo1, dinv, t16, N);
    agg128h<<<AB, 256, 0, stream>>>(t16, row_ptr, col, dinv, b1, bufA, N);

    gemm_mfma<__half, 128><<<GB, 256, 0, stream>>>(bufA, whiM1, wloM1, dinv, t16, N);
    agg128h<<<AB, 256, 0, stream>>>(t16, row_ptr, col, dinv, bm1, bufA, N);

    gemm_mfma<__half, 128><<<GB, 256, 0, stream>>>(bufA, whiM2, wloM2, dinv, t16, N);
    agg128h<<<AB, 256, 0, stream>>>(t16, row_ptr, col, dinv, bm2, bufA, N);

    gemm_mfma<__half, 64><<<GB, 256, 0, stream>>>(bufA, whi2, wlo2, dinv, t16, N);
    agg64h<<<AB, 256, 0, stream>>>(t16, row_ptr, col, dinv, b2, out, N);
}